// Round 2
// 167.862 us; speedup vs baseline: 1.0787x; 1.0787x over previous
//
#include <hip/hip_runtime.h>
#include <math.h>

typedef __attribute__((ext_vector_type(8))) short bf16x8;
typedef __attribute__((ext_vector_type(4))) short bf16x4;
typedef __attribute__((ext_vector_type(4))) float f32x4;

#define MFMA16(a, b, c) __builtin_amdgcn_mfma_f32_16x16x32_bf16(a, b, c, 0, 0, 0)

#define GLOAD_LDS16(g, l)                                                        \
    __builtin_amdgcn_global_load_lds(                                            \
        (const __attribute__((address_space(1))) void*)(g),                      \
        (__attribute__((address_space(3))) void*)(l), 16, 0, 0)

__device__ __forceinline__ short f2bf(float f) {
    union { float f; unsigned u; } x; x.f = f;
    unsigned r = (x.u + 0x7fffu + ((x.u >> 16) & 1u)) >> 16;
    return (short)r;
}

// ---------------- elementwise fp32 -> bf16 ----------------
__global__ __launch_bounds__(256) void convert_bf16_kernel(
    const float* __restrict__ in, short* __restrict__ out, int n4) {
    int i = blockIdx.x * 256 + threadIdx.x;
    if (i >= n4) return;
    float4 v = ((const float4*)in)[i];
    bf16x4 o;
    o[0] = f2bf(v.x); o[1] = f2bf(v.y); o[2] = f2bf(v.z); o[3] = f2bf(v.w);
    ((bf16x4*)out)[i] = o;
}

// ------- fused transpose+convert for both weights: W[K][N] fp32 -> Wt[N][K] bf16 -----
__global__ __launch_bounds__(256) void transpose_w2_kernel(
    const float* __restrict__ Wa, const float* __restrict__ Wp,
    short* __restrict__ WaT, short* __restrict__ WpT) {
    __shared__ float tile[32][33];
    const float* W; short* Wt; int N, xb;
    if (blockIdx.x < 96) { W = Wa; Wt = WaT; N = 3072; xb = blockIdx.x; }
    else                 { W = Wp; Wt = WpT; N = 1024; xb = blockIdx.x - 96; }
    const int K = 1024;
    int c = threadIdx.x & 31, r0 = threadIdx.x >> 5;
    int n0 = xb << 5, k0 = blockIdx.y << 5;
#pragma unroll
    for (int i = 0; i < 4; i++) {
        int r = r0 + i * 8;
        tile[r][c] = W[(long)(k0 + r) * N + n0 + c];
    }
    __syncthreads();
#pragma unroll
    for (int i = 0; i < 4; i++) {
        int r = r0 + i * 8;
        Wt[(long)(n0 + r) * K + k0 + c] = f2bf(tile[c][r]);
    }
}

// ---------------- QKV GEMM: 256x256 tile, 8-phase counted-vmcnt pipeline ----------------
// Grid 12x16, 512 threads (8 waves, 2M x 4N), BK=64, K=1024 (16 K-tiles).
// n-blocks 0-7 -> Q (scaled) / K rows into QK[4096][2048] bf16;
// n-blocks 8-11 -> V: per-wave LDS transpose -> VT[B,H,64,2048] bf16 (one head per wave).
// Schedule per K-tile (4 phases, 2 stage issues each, raw s_barrier only — no vmcnt(0)
// drain in steady state):
//   P0: issue B0,B1(t+1); read Bfrags+A mt0,1; bar; 16 MFMA; bar
//   P1: issue B2,B3;      read A mt2,3;        bar; 16 MFMA; bar
//   P2: vmcnt(4); bar; issue A0,A2; read A mt4,5; 16 MFMA; bar
//   P3: issue A1,A3; read A mt6,7; bar; 16 MFMA; vmcnt(2); bar
// vmcnt(4) drains exactly this tile's late A-quarters (issued prev P3); vmcnt(2)
// drains next tile's B+A0/A2 while keeping its A1/A3 in flight across the switch.

#define SBAR() __builtin_amdgcn_s_barrier()
#define PRIO(x) __builtin_amdgcn_s_setprio(x)
#define VMW4 asm volatile("s_waitcnt vmcnt(4)" ::: "memory")
#define VMW2 asm volatile("s_waitcnt vmcnt(2)" ::: "memory")
#define VMW0 asm volatile("s_waitcnt vmcnt(0)" ::: "memory")
#define NOPS ((void)0)

#define LDA8(IDX) (*(const bf16x8*)&ls[(IDX)])
#define SA(q, k1v, nbv) GLOAD_LDS16(Ags + (size_t)(q) * 65536 + (k1v), &ls[(nbv) + (q) * 4096 + swd])
#define SB(q, k1v, nbv) GLOAD_LDS16(Bgs + (size_t)(q) * 65536 + (k1v), &ls[(nbv) + 32768 + (q) * 4096 + swd])

#define PHASE_MFMA(M0_, M1_, aa0, ba0, aa1, ba1)              \
    PRIO(1);                                                  \
    acc[M0_][0] = MFMA16(aa0, b00, acc[M0_][0]);              \
    acc[M0_][1] = MFMA16(aa0, b10, acc[M0_][1]);              \
    acc[M0_][2] = MFMA16(aa0, b20, acc[M0_][2]);              \
    acc[M0_][3] = MFMA16(aa0, b30, acc[M0_][3]);              \
    acc[M1_][0] = MFMA16(ba0, b00, acc[M1_][0]);              \
    acc[M1_][1] = MFMA16(ba0, b10, acc[M1_][1]);              \
    acc[M1_][2] = MFMA16(ba0, b20, acc[M1_][2]);              \
    acc[M1_][3] = MFMA16(ba0, b30, acc[M1_][3]);              \
    acc[M0_][0] = MFMA16(aa1, b01, acc[M0_][0]);              \
    acc[M0_][1] = MFMA16(aa1, b11, acc[M0_][1]);              \
    acc[M0_][2] = MFMA16(aa1, b21, acc[M0_][2]);              \
    acc[M0_][3] = MFMA16(aa1, b31, acc[M0_][3]);              \
    acc[M1_][0] = MFMA16(ba1, b01, acc[M1_][0]);              \
    acc[M1_][1] = MFMA16(ba1, b11, acc[M1_][1]);              \
    acc[M1_][2] = MFMA16(ba1, b21, acc[M1_][2]);              \
    acc[M1_][3] = MFMA16(ba1, b31, acc[M1_][3]);              \
    PRIO(0);

#define KTILE(T, STG, VMP2, VMTAIL) do {                                              \
    const int cb = ((T) & 1) << 14;                                                   \
    const int nb = cb ^ 16384;                                                        \
    const int k1 = ((T) + 1) << 6;                                                    \
    (void)nb; (void)k1;                                                               \
    /* ---- P0 ---- */                                                                \
    if (STG) { SB(0, k1, nb); SB(1, k1, nb); }                                        \
    const bf16x8 b00 = LDA8(cb + 32768 + bro + sw0);                                  \
    const bf16x8 b01 = LDA8(cb + 32768 + bro + sw1);                                  \
    const bf16x8 b10 = LDA8(cb + 32768 + bro + 1024 + sw0);                           \
    const bf16x8 b11 = LDA8(cb + 32768 + bro + 1024 + sw1);                           \
    const bf16x8 b20 = LDA8(cb + 32768 + bro + 2048 + sw0);                           \
    const bf16x8 b21 = LDA8(cb + 32768 + bro + 2048 + sw1);                           \
    const bf16x8 b30 = LDA8(cb + 32768 + bro + 3072 + sw0);                           \
    const bf16x8 b31 = LDA8(cb + 32768 + bro + 3072 + sw1);                           \
    {                                                                                 \
        bf16x8 x0 = LDA8(cb + aro + sw0), x1 = LDA8(cb + aro + sw1);                  \
        bf16x8 y0 = LDA8(cb + aro + 1024 + sw0), y1 = LDA8(cb + aro + 1024 + sw1);    \
        SBAR();                                                                       \
        PHASE_MFMA(0, 1, x0, y0, x1, y1)                                              \
        SBAR();                                                                       \
    }                                                                                 \
    /* ---- P1 ---- */                                                                \
    if (STG) { SB(2, k1, nb); SB(3, k1, nb); }                                        \
    {                                                                                 \
        bf16x8 x0 = LDA8(cb + aro + 2048 + sw0), x1 = LDA8(cb + aro + 2048 + sw1);    \
        bf16x8 y0 = LDA8(cb + aro + 3072 + sw0), y1 = LDA8(cb + aro + 3072 + sw1);    \
        SBAR();                                                                       \
        PHASE_MFMA(2, 3, x0, y0, x1, y1)                                              \
        SBAR();                                                                       \
    }                                                                                 \
    /* ---- P2 ---- */                                                                \
    VMP2;                                                                             \
    SBAR();                                                                           \
    if (STG) { SA(0, k1, nb); SA(2, k1, nb); }                                        \
    {                                                                                 \
        bf16x8 x0 = LDA8(cb + aro + 4096 + sw0), x1 = LDA8(cb + aro + 4096 + sw1);    \
        bf16x8 y0 = LDA8(cb + aro + 5120 + sw0), y1 = LDA8(cb + aro + 5120 + sw1);    \
        PHASE_MFMA(4, 5, x0, y0, x1, y1)                                              \
        SBAR();                                                                       \
    }                                                                                 \
    /* ---- P3 ---- */                                                                \
    if (STG) { SA(1, k1, nb); SA(3, k1, nb); }                                        \
    {                                                                                 \
        bf16x8 x0 = LDA8(cb + aro + 6144 + sw0), x1 = LDA8(cb + aro + 6144 + sw1);    \
        bf16x8 y0 = LDA8(cb + aro + 7168 + sw0), y1 = LDA8(cb + aro + 7168 + sw1);    \
        SBAR();                                                                       \
        PHASE_MFMA(6, 7, x0, y0, x1, y1)                                              \
        VMTAIL;                                                                       \
        SBAR();                                                                       \
    }                                                                                 \
} while (0)

__global__ __launch_bounds__(512, 2) void gemm_qkv_kernel(
    const short* __restrict__ A, const short* __restrict__ Bt,
    const float* __restrict__ bias,
    short* __restrict__ QK, short* __restrict__ VTb) {
    __shared__ __align__(16) short ls[65536];  // 128 KB: A[2][256*64] | B[2][256*64]
    const int tid = threadIdx.x;
    const int lane = tid & 63, l15 = lane & 15, quad = lane >> 4;
    const int w = tid >> 6, wm = w >> 2, wn = w & 3;
    const int m0 = blockIdx.y * 256, n0 = blockIdx.x * 256;
    const int e = l15 & 7;
    // staging geometry: 64-row quarter per issue, 8 rows per wave, XOR-preswizzled src
    const int sgr = (w << 3) + (lane >> 3);
    const int sgc = ((lane & 7) ^ (lane >> 3)) << 3;
    const int swd = w << 9;  // wave-uniform LDS offset within a quarter (shorts)
    const short* Ags = A + (size_t)(m0 + sgr) * 1024 + sgc;
    const short* Bgs = Bt + (size_t)(n0 + sgr) * 1024 + sgc;
    // fragment-read bases (same verified swizzle family as before)
    const int aro = (wm * 128 + l15) << 6;
    const int bro = (wn * 64 + l15) << 6;
    const int sw0 = (quad ^ e) << 3;
    const int sw1 = ((4 + quad) ^ e) << 3;

    f32x4 acc[8][4];
#pragma unroll
    for (int i = 0; i < 8; i++)
#pragma unroll
        for (int j = 0; j < 4; j++) acc[i][j] = (f32x4){0.f, 0.f, 0.f, 0.f};

    // prologue: stage K-tile 0 into buf0; order B0..B3, A0, A2, A1, A3 so that
    // vmcnt(2) leaves A1,A3 (needed only at P2/P3) in flight.
    SB(0, 0, 0); SB(1, 0, 0); SB(2, 0, 0); SB(3, 0, 0);
    SA(0, 0, 0); SA(2, 0, 0); SA(1, 0, 0); SA(3, 0, 0);
    VMW2;
    SBAR();

#pragma unroll 2
    for (int t = 0; t < 14; ++t) { KTILE(t, 1, VMW4, VMW2); }
    KTILE(14, 1, VMW4, VMW0);   // drain fully before the no-stage final tile
    KTILE(15, 0, VMW0, NOPS);

    __syncthreads();  // protects LDS reuse by the V epilogue

    if (n0 < 2048) {
        const float scale = (n0 < 1024) ? 0.18033688011112042f : 1.0f;  // 1/8 * log2(e)
#pragma unroll
        for (int nt = 0; nt < 4; nt++) {
            const int nn = n0 + wn * 64 + nt * 16 + l15;
            const float bv = bias[nn];
#pragma unroll
            for (int mt = 0; mt < 8; mt++)
#pragma unroll
                for (int r = 0; r < 4; r++) {
                    const int mm = m0 + wm * 128 + mt * 16 + quad * 4 + r;
                    QK[(long)mm * 2048 + nn] = f2bf((acc[mt][nt][r] + bv) * scale);
                }
        }
    } else {
        // each wave owns exactly one head: 128(s) x 64(d) -> VT[bh][d][s].
        // Two 64-s halves through a [64 d][68] per-wave LDS buffer (fits: 8x4352
        // shorts = 69.6 KB). Wave-local ds_write->ds_read->ds_write ordering is
        // in-order per wave; no cross-wave sharing.
        short* vt = &ls[w * 4352];
        const int hh = ((n0 - 2048) >> 6) + wn;
        const int bb = m0 >> 11;
        const int srow = (m0 & 2047) + wm * 128;
        const int sloc = (lane & 7) << 3;
#pragma unroll
        for (int half = 0; half < 2; half++) {
#pragma unroll
            for (int nt = 0; nt < 4; nt++) {
                const int nn = n0 + wn * 64 + nt * 16 + l15;
                const float bv = bias[nn];
                const int d_ = nt * 16 + l15;
#pragma unroll
                for (int mt = 0; mt < 4; mt++) {
                    const int mtg = half * 4 + mt;
                    bf16x4 pk;
#pragma unroll
                    for (int r = 0; r < 4; r++) pk[r] = f2bf(acc[mtg][nt][r] + bv);
                    *(bf16x4*)&vt[d_ * 68 + mt * 16 + quad * 4] = pk;
                }
            }
#pragma unroll
            for (int i = 0; i < 8; i++) {
                const int d = i * 8 + (lane >> 3);
                bf16x8 vv = *(const bf16x8*)&vt[d * 68 + sloc];
                *(bf16x8*)&VTb[((size_t)(bb * 16 + hh) * 64 + d) * 2048 + srow + half * 64 + sloc] = vv;
            }
        }
    }
}

// ---------------- proj GEMM: 128x64 tile (512 blocks = 2/CU) ----------------
__global__ __launch_bounds__(256) void gemm_proj_kernel(
    const short* __restrict__ A, const short* __restrict__ Bt,
    const float* __restrict__ bias, float* __restrict__ outF) {
    __shared__ __align__(16) short lsA[128 * 64];
    __shared__ __align__(16) short lsB[64 * 64];
    const int tid = threadIdx.x;
    const int lane = tid & 63, l15 = lane & 15, quad = lane >> 4, w = tid >> 6;
    const int m0 = blockIdx.y * 128, n0 = blockIdx.x * 64;
    const int e = l15 & 7;
    const int lrow = lane >> 3;
    const int lgcol = ((lane & 7) ^ lrow) << 3;

    f32x4 acc[2][4];
#pragma unroll
    for (int i = 0; i < 2; i++)
#pragma unroll
        for (int j = 0; j < 4; j++) acc[i][j] = (f32x4){0.f, 0.f, 0.f, 0.f};

    for (int k0 = 0; k0 < 1024; k0 += 64) {
#pragma unroll
        for (int ii = 0; ii < 4; ii++) {
            const int i = (w << 2) + ii;
            const int grow = (i << 3) + lrow;
            GLOAD_LDS16(&A[(size_t)(m0 + grow) * 1024 + k0 + lgcol], &lsA[i * 512]);
        }
#pragma unroll
        for (int ii = 0; ii < 2; ii++) {
            const int i = (w << 1) + ii;
            const int grow = (i << 3) + lrow;
            GLOAD_LDS16(&Bt[(size_t)(n0 + grow) * 1024 + k0 + lgcol], &lsB[i * 512]);
        }
        __syncthreads();
#pragma unroll
        for (int kk = 0; kk < 64; kk += 32) {
            const int kb = kk >> 3;
            const int sw = (((kb + quad) ^ e) << 3);
            bf16x8 af[2], bfr[4];
#pragma unroll
            for (int mt = 0; mt < 2; mt++)
                af[mt] = *(const bf16x8*)&lsA[(w * 32 + mt * 16 + l15) * 64 + sw];
#pragma unroll
            for (int nt = 0; nt < 4; nt++)
                bfr[nt] = *(const bf16x8*)&lsB[(nt * 16 + l15) * 64 + sw];
#pragma unroll
            for (int mt = 0; mt < 2; mt++)
#pragma unroll
                for (int nt = 0; nt < 4; nt++)
                    acc[mt][nt] = MFMA16(af[mt], bfr[nt], acc[mt][nt]);
        }
        __syncthreads();
    }

#pragma unroll
    for (int nt = 0; nt < 4; nt++) {
        int nn = n0 + nt * 16 + l15;
        float bv = bias[nn];
#pragma unroll
        for (int mt = 0; mt < 2; mt++)
#pragma unroll
            for (int r = 0; r < 4; r++) {
                int mm = m0 + w * 32 + mt * 16 + quad * 4 + r;
                outF[(long)mm * 1024 + nn] = acc[mt][nt][r] + bv;
            }
    }
}

// ---------------- causal flash attention (R5 structure, best measured) ----------------
__global__ __launch_bounds__(256, 4) void attn_kernel(
    const short* __restrict__ QK, const short* __restrict__ VT,
    short* __restrict__ Ao) {
    __shared__ __align__(16) short Kt[2][64 * 64];  // 16 KB
    __shared__ __align__(16) short Vt[2][64 * 64];  // 16 KB
    __shared__ __align__(16) short Pt[4][1024];     // 8 KB (per-wave private)
    const int tid = threadIdx.x;
    const int lane = tid & 63, l15 = lane & 15, quad = lane >> 4, w = tid >> 6;
    const int bx = blockIdx.x;
    const int qt = 31 - (bx >> 5);  // heavy q-tiles first
    const int hb = bx & 31;         // b*16 + h
    const int b = hb >> 4, h = hb & 15;
    const size_t rowbase = (size_t)b * 2048 * 2048 + h * 64;
    const short* Qb = QK + rowbase;          // q row: + qs*2048 + d
    const short* Kb = QK + rowbase + 1024;   // k row: + ks*2048 + d
    const short* Vh = VT + (size_t)hb * 64 * 2048;  // [64][2048]
    short* Pw = &Pt[w][0];
    const int e = l15 & 7;

    const int srow0 = tid >> 3, sc40 = (tid & 7) ^ (srow0 & 7);
    const int srow1 = srow0 + 32, sc41 = (tid & 7) ^ (srow1 & 7);
    const int sdst0 = srow0 * 64 + ((tid & 7) << 3);
    const int sdst1 = srow1 * 64 + ((tid & 7) << 3);

    const long qr = (long)(qt * 64 + w * 16 + l15) * 2048;
    bf16x8 qf0 = *(const bf16x8*)&Qb[qr + quad * 8];
    bf16x8 qf1 = *(const bf16x8*)&Qb[qr + 32 + quad * 8];

    float l = 0.f;
    f32x4 o[4];
#pragma unroll
    for (int dt = 0; dt < 4; dt++) o[dt] = (f32x4){0.f, 0.f, 0.f, 0.f};

    const int nc = qt + 1;

    *(bf16x8*)&Kt[0][sdst0] = *(const bf16x8*)&Kb[(size_t)srow0 * 2048 + sc40 * 8];
    *(bf16x8*)&Kt[0][sdst1] = *(const bf16x8*)&Kb[(size_t)srow1 * 2048 + sc41 * 8];
    *(bf16x8*)&Vt[0][sdst0] = *(const bf16x8*)&Vh[srow0 * 2048 + sc40 * 8];
    *(bf16x8*)&Vt[0][sdst1] = *(const bf16x8*)&Vh[srow1 * 2048 + sc41 * 8];
    __syncthreads();

    for (int c = 0; c < nc; c++) {
        const short* Kc = &Kt[c & 1][0];
        const short* Vc = &Vt[c & 1][0];
        const bool more = (c + 1 < nc);
        bf16x8 kr0, kr1, vr0, vr1;
        if (more) {
            const int k2 = (c + 1) * 64;
            kr0 = *(const bf16x8*)&Kb[(size_t)(k2 + srow0) * 2048 + sc40 * 8];
            kr1 = *(const bf16x8*)&Kb[(size_t)(k2 + srow1) * 2048 + sc41 * 8];
            vr0 = *(const bf16x8*)&Vh[srow0 * 2048 + k2 + sc40 * 8];
            vr1 = *(const bf16x8*)&Vh[srow1 * 2048 + k2 + sc41 * 8];
        }

        f32x4 s[4];
#pragma unroll
        for (int t = 0; t < 4; t++) {
            bf16x8 k0f = *(const bf16x8*)&Kc[(t * 16 + l15) * 64 + ((quad ^ e) << 3)];
            bf16x8 k1f = *(const bf16x8*)&Kc[(t * 16 + l15) * 64 + (((4 + quad) ^ e) << 3)];
            f32x4 z = (f32x4){0.f, 0.f, 0.f, 0.f};
            z = MFMA16(k0f, qf0, z);
            z = MFMA16(k1f, qf1, z);
            s[t] = z;
        }

        if (c == nc - 1) {
#pragma unroll
            for (int t = 0; t < 4; t++)
#pragma unroll
                for (int r = 0; r < 4; r++)
                    if (t * 16 + quad * 4 + r > w * 16 + l15) s[t][r] = -INFINITY;
        }

#pragma unroll
        for (int t = 0; t < 4; t++) {
            bf16x4 pw;
#pragma unroll
            for (int r = 0; r < 4; r++) {
                float pv = __builtin_amdgcn_exp2f(s[t][r]);
                l += pv;
                pw[r] = f2bf(pv);
            }
            *(bf16x4*)&Pw[l15 * 64 + (((2 * t + (quad >> 1)) ^ e) << 3) + ((quad & 1) << 2)] = pw;
        }

        bf16x8 pf0 = *(const bf16x8*)&Pw[l15 * 64 + ((quad ^ e) << 3)];
        bf16x8 pf1 = *(const bf16x8*)&Pw[l15 * 64 + (((4 + quad) ^ e) << 3)];
#pragma unroll
        for (int dt = 0; dt < 4; dt++) {
            bf16x8 v0f = *(const bf16x8*)&Vc[(dt * 16 + l15) * 64 + ((quad ^ e) << 3)];
            bf16x8 v1f = *(const bf16x8*)&Vc[(dt * 16 + l15) * 64 + (((4 + quad) ^ e) << 3)];
            o[dt] = MFMA16(v0f, pf0, o[dt]);
            o[dt] = MFMA16(v1f, pf1, o[dt]);
        }

        if (more) {
            short* Kn = &Kt[(c + 1) & 1][0];
            short* Vn = &Vt[(c + 1) & 1][0];
            *(bf16x8*)&Kn[sdst0] = kr0;
            *(bf16x8*)&Kn[sdst1] = kr1;
            *(bf16x8*)&Vn[sdst0] = vr0;
            *(bf16x8*)&Vn[sdst1] = vr1;
        }
        __syncthreads();
    }

    l += __shfl_xor(l, 16);
    l += __shfl_xor(l, 32);
    const float rl = 1.f / l;

    const int qs = qt * 64 + w * 16 + l15;
    const long base = ((long)(b * 2048 + qs)) * 1024 + h * 64;
#pragma unroll
    for (int dt = 0; dt < 4; dt++) {
        bf16x4 wv;
#pragma unroll
        for (int r = 0; r < 4; r++) wv[r] = f2bf(o[dt][r] * rl);
        *(bf16x4*)&Ao[base + dt * 16 + quad * 4] = wv;
    }
}

extern "C" void kernel_launch(void* const* d_in, const int* in_sizes, int n_in,
                              void* d_out, int out_size, void* d_ws, size_t ws_size,
                              hipStream_t stream) {
    const float* hs = (const float*)d_in[0];
    const float* W_attn = (const float*)d_in[1];
    const float* b_attn = (const float*)d_in[2];
    const float* W_proj = (const float*)d_in[3];
    const float* b_proj = (const float*)d_in[4];
    float* out = (float*)d_out;

    const size_t MB = 1024 * 1024;
    char* ws = (char*)d_ws;
    short* hs_bf = (short*)ws;                   // [0,8): hs bf16; later attn_o (alias)
    short* attn_o = hs_bf;
    short* WaT = (short*)(ws + 8 * MB);          // [8,14): W_attn^T bf16
    short* WpT = (short*)(ws + 14 * MB);         // [14,16): W_proj^T bf16
    short* QK = (short*)(ws + 16 * MB);          // [16,32): [4096][2048] bf16
    short* VTb = (short*)(ws + 32 * MB);         // [32,40): [32][64][2048] bf16

    convert_bf16_kernel<<<4096, 256, 0, stream>>>(hs, hs_bf, 1048576);
    transpose_w2_kernel<<<dim3(128, 32), 256, 0, stream>>>(W_attn, W_proj, WaT, WpT);
    gemm_qkv_kernel<<<dim3(12, 16), 512, 0, stream>>>(hs_bf, WaT, b_attn, QK, VTb);
    attn_kernel<<<1024, 256, 0, stream>>>(QK, VTb, attn_o);
    gemm_proj_kernel<<<dim3(16, 32), 256, 0, stream>>>(attn_o, WpT, b_proj, out);
}